// Round 21
// baseline (558.829 us; speedup 1.0000x reference)
//
#include <hip/hip_runtime.h>
#include <hip/hip_bf16.h>
#include <stdint.h>
#include <stddef.h>

typedef __attribute__((ext_vector_type(8))) __bf16 bf16x8;
typedef __attribute__((ext_vector_type(4))) float f32x4;
typedef __attribute__((ext_vector_type(16))) float f32x16;

#define MFMA16(a, b, c) __builtin_amdgcn_mfma_f32_16x16x32_bf16((a), (b), (c), 0, 0, 0)
#define MFMA32(a, b, c) __builtin_amdgcn_mfma_f32_32x32x16_bf16((a), (b), (c), 0, 0, 0)

static constexpr int Bc = 4, Nc = 4096, Dc = 1024, Hc = 16, HDc = 64;
static constexpr size_t XSZ = (size_t)Bc * Nc * Dc;   // 16,777,216
static constexpr size_t W1SZ = (size_t)3 * Dc * Dc;   //  3,145,728
static constexpr size_t W2SZ = (size_t)Dc * Dc;       //  1,048,576

__device__ __forceinline__ uint16_t f2bf(float f) {
  __bf16 h = (__bf16)f;
  return __builtin_bit_cast(uint16_t, h);
}

// raw v_exp_f32 (no libm edge-case code; inputs here are finite, bounded)
__device__ __forceinline__ float fexp2(float x) {
#if __has_builtin(__builtin_amdgcn_exp2f)
  return __builtin_amdgcn_exp2f(x);
#else
  return __builtin_exp2f(x);
#endif
}

// async global->LDS, 16B per lane. LDS dest must be wave-uniform base + lane*16.
__device__ __forceinline__ void gload16(const void* g, void* l) {
  __builtin_amdgcn_global_load_lds(
      (__attribute__((address_space(1))) void*)(g),
      (__attribute__((address_space(3))) void*)(l), 16, 0, 0);
}

// ---------------------------------------------------------------------------
// fused f32 -> bf16 convert for x, W_qkv, W_out (one launch, flat-indexed)
// ---------------------------------------------------------------------------
__global__ __launch_bounds__(256) void cvt_all(
    const float* __restrict__ x, const float* __restrict__ w1,
    const float* __restrict__ w2, uint16_t* __restrict__ xb,
    uint16_t* __restrict__ w1b, uint16_t* __restrict__ w2b) {
  const size_t XN = XSZ / 8, W1N = W1SZ / 8, W2N = W2SZ / 8;
  size_t i = (size_t)blockIdx.x * 256 + threadIdx.x;
  const float* src;
  uint16_t* dst;
  if (i < XN) {
    src = x; dst = xb;
  } else if (i < XN + W1N) {
    src = w1; dst = w1b; i -= XN;
  } else if (i < XN + W1N + W2N) {
    src = w2; dst = w2b; i -= XN + W1N;
  } else {
    return;
  }
  const float4 a = *(const float4*)(src + i * 8);
  const float4 b = *(const float4*)(src + i * 8 + 4);
  union { uint16_t u[8]; uint4 v; } o;
  o.u[0] = f2bf(a.x); o.u[1] = f2bf(a.y); o.u[2] = f2bf(a.z); o.u[3] = f2bf(a.w);
  o.u[4] = f2bf(b.x); o.u[5] = f2bf(b.y); o.u[6] = f2bf(b.z); o.u[7] = f2bf(b.w);
  *(uint4*)(dst + i * 8) = o.v;
}

// ---------------------------------------------------------------------------
// BT-GEMM: C[m, e] = sum_k A[m, k] * Bw[e, k].  128x128 tile, BK=64, 4 waves,
// (r21) T3 2-phase double-buffered staging: stage(t+1) issued right after the
// single per-tile barrier so global_load_lds flies under the MFMA compute
// (the attn-proven dbuf pattern; was barrier->stage->barrier->compute).
// EPI=0: QKV projection epilogue -> RoPE (f32 rot) -> Q/K [B,H,N,HD] bf16,
//        Q pre-scaled by 0.125*log2(e) (exp2-domain softmax),
//        V transposed [B,H,HD,N] bf16, kv-axis PRE-INTERLEAVED per 64-tile
//        so attn stages V with global_load_lds directly.
// EPI=1: bias add (f32) -> Out [M, 1024] f32
// ---------------------------------------------------------------------------
template <int EPI>
__global__ __launch_bounds__(256, 2) void gemm_bt(
    const uint16_t* __restrict__ A, const uint16_t* __restrict__ Bw, int K,
    const float* __restrict__ rot, uint16_t* __restrict__ Qb,
    uint16_t* __restrict__ Kb, uint16_t* __restrict__ Vg,
    const float* __restrict__ bias, float* __restrict__ Out) {
  __shared__ __align__(16) uint16_t As[2][128 * 64];
  __shared__ __align__(16) uint16_t Bs[2][128 * 64];
  const int tid = threadIdx.x;
  const int lane = tid & 63, wave = tid >> 6;
  const int l15 = lane & 15, g = lane >> 4;
  const int wr = wave >> 1, wc = wave & 1;
  const int m0 = blockIdx.y * 128;
  const int n0 = blockIdx.x * 128;

  f32x4 acc[4][4];
  const f32x4 fz = {0.f, 0.f, 0.f, 0.f};
#pragma unroll
  for (int i = 0; i < 4; ++i)
#pragma unroll
    for (int j = 0; j < 4; ++j) acc[i][j] = fz;

  // stage A/B K-slab kt into LDS buffer buf (linear dest, pre-swz source)
  auto stageg = [&](int buf, int kt) {
#pragma unroll
    for (int i = 0; i < 4; ++i) {
      const int chunk = tid + i * 256;  // 0..1023 : 128 rows x 8 chunks(16B)
      const int r = chunk >> 3, c = chunk & 7;
      const int cs = c ^ (r & 7);
      gload16(A + (size_t)(m0 + r) * K + kt + cs * 8, &As[buf][chunk * 8]);
      gload16(Bw + (size_t)(n0 + r) * K + kt + cs * 8, &Bs[buf][chunk * 8]);
    }
  };

  stageg(0, 0);
  int cur = 0;
  for (int kt = 0; kt < K; kt += 64) {
    __syncthreads();  // drains vmcnt: slab kt visible; prev reads closed
    if (kt + 64 < K) stageg(cur ^ 1, kt + 64);

    bf16x8 af[4][2], bfr[4][2];
#pragma unroll
    for (int mi = 0; mi < 4; ++mi)
#pragma unroll
      for (int kk = 0; kk < 2; ++kk) {
        const int r = wr * 64 + mi * 16 + l15;
        const int ca = (kk * 4 + g) ^ (r & 7);
        af[mi][kk] = *(const bf16x8*)((const char*)&As[cur][0] + r * 128 + ca * 16);
        const int r2 = wc * 64 + mi * 16 + l15;
        const int cb = (kk * 4 + g) ^ (r2 & 7);
        bfr[mi][kk] = *(const bf16x8*)((const char*)&Bs[cur][0] + r2 * 128 + cb * 16);
      }
    __builtin_amdgcn_s_setprio(1);
#pragma unroll
    for (int mi = 0; mi < 4; ++mi)
#pragma unroll
      for (int nj = 0; nj < 4; ++nj)
#pragma unroll
        for (int kk = 0; kk < 2; ++kk)
          acc[mi][nj] = MFMA16(af[mi][kk], bfr[nj][kk], acc[mi][nj]);
    __builtin_amdgcn_s_setprio(0);
    cur ^= 1;
  }

  if (EPI == 0) {
    // C rows m -> (b, n); cols e -> (part, h, hd). RoPE pair is lane^1.
    const int b = m0 >> 12;  // 4096 rows per batch, 128 | 4096 -> uniform
#pragma unroll
    for (int nj = 0; nj < 4; ++nj) {
      const int e = n0 + wc * 64 + nj * 16 + l15;
      const int part = e >> 10;           // wave-uniform (16-col tile)
      const int d = e & 1023;
      const int h = d >> 6, hd = d & 63;
      // exp2-domain: fold 0.125*log2(e) into Q
      const float sc = (part == 0) ? 0.18033688011112042f : 1.0f;
#pragma unroll
      for (int mi = 0; mi < 4; ++mi) {
        if (part == 2) {
          // V transposed [B,H,HD,N], kv pre-interleaved per 64-tile:
          // pack of 4 consecutive n at 4-aligned nb lands contiguously at pos.
          const int nb = (m0 & 4095) + wr * 64 + mi * 16 + g * 4;
          const int vv = nb & 63;
          const int pos = (nb & ~63) + (2 * (vv >> 4) + ((vv >> 2) & 1)) * 8 +
                          ((vv >> 3) & 1) * 4;
          uint2 pv;
          pv.x = (uint32_t)f2bf(acc[mi][nj][0]) |
                 ((uint32_t)f2bf(acc[mi][nj][1]) << 16);
          pv.y = (uint32_t)f2bf(acc[mi][nj][2]) |
                 ((uint32_t)f2bf(acc[mi][nj][3]) << 16);
          *(uint2*)(Vg + ((size_t)(b * Hc + h) * HDc + hd) * Nc + pos) = pv;
        } else {
          uint16_t* dst = (part == 0) ? Qb : Kb;
          const size_t base = ((size_t)(b * Hc + h) * Nc) * HDc + hd;
#pragma unroll
          for (int rg = 0; rg < 4; ++rg) {
            const int m = m0 + wr * 64 + mi * 16 + g * 4 + rg;
            const int n = m & (Nc - 1);
            const float val = acc[mi][nj][rg];
            const float partner = __shfl_xor(val, 1);
            const float x2 = (e & 1) ? partner : -partner;
            const float2 cs =
                *(const float2*)(rot + ((size_t)(b * Nc + n) * Dc + d) * 2);
            dst[base + (size_t)n * HDc] = f2bf((val * cs.x + x2 * cs.y) * sc);
          }
        }
      }
    }
  } else {
#pragma unroll
    for (int nj = 0; nj < 4; ++nj) {
      const int e = n0 + wc * 64 + nj * 16 + l15;
      const float bia = bias[e];
#pragma unroll
      for (int mi = 0; mi < 4; ++mi)
#pragma unroll
        for (int rg = 0; rg < 4; ++rg) {
          const int m = m0 + wr * 64 + mi * 16 + g * 4 + rg;
          Out[(size_t)m * Dc + e] = acc[mi][nj][rg] + bia;
        }
    }
  }
}

// ---------------------------------------------------------------------------
// Flash attention — best-known config (r17 + epilogue lrow-combine):
// 32x32x16 MFMA, in-register P, no-max exp2 softmax, VALU denominator,
// T15 PV-deferral, runtime-cur dbuf, launch_bounds(256,3), XCD-clustered
// grid, pre-interleaved V via global_load_lds.
// ---------------------------------------------------------------------------
__global__ __launch_bounds__(256, 3) void attn_fa(
    const uint16_t* __restrict__ Qb, const uint16_t* __restrict__ Kb,
    const uint16_t* __restrict__ Vg, uint16_t* __restrict__ Ob) {
  __shared__ __align__(16) uint16_t Ks[2][64 * 64];  // [kv][d], chunk-swizzled
  __shared__ __align__(16) uint16_t Vt[2][64 * 64];  // [d][kv-interleaved]
  const int tid = threadIdx.x;
  const int lane = tid & 63, wave = tid >> 6;
  const int l31 = lane & 31, hi = lane >> 5;
  const int sw = l31 & 7;  // swizzle index (row&7 for all row sets used)
  // XCD-clustered bijective remap: id%8 = XCD slot; all 32 q-blocks of a bh
  // land on one XCD -> that L2 only holds its own 8 bh's K/V (~6MB).
  const int id = blockIdx.x;
  const int kk2 = id >> 3;
  const int bh = (id & 7) + 8 * (kk2 >> 5);
  const int q0 = (kk2 & 31) * 128;
  const size_t bhN = (size_t)bh * Nc;
  const size_t bhHD = (size_t)bh * HDc;

  // Q B-fragments (col = q = l31, k(d) = ks*16 + hi*8 + j), register-resident
  bf16x8 qf[4];
#pragma unroll
  for (int ks = 0; ks < 4; ++ks)
    qf[ks] = *(const bf16x8*)(Qb + (bhN + q0 + wave * 32 + l31) * HDc +
                              ks * 16 + hi * 8);

  // persistent zero C-operand for the QK^T MFMA chain
  const f32x16 fzv = {};

  f32x16 O16[2] = {{}, {}};
  float lrow = 0.f;  // per-lane partial; partner (^32) combined in epilogue

  // deferred-PV state: previous tile's P fragments and V fragments.
  // Zero-init so the first iteration's PV(-1) contributes exactly 0.
  bf16x8 paP[4], vfP[2][4];
  {
    const bf16x8 bz = {};
#pragma unroll
    for (int m = 0; m < 4; ++m) { paP[m] = bz; vfP[0][m] = bz; vfP[1][m] = bz; }
  }

  // stage K and V (both gload_lds: linear dest, pre-swizzled source; V's
  // interleave was already applied by the gemm epilogue).
  auto stage = [&](uint16_t* ksd, uint16_t* vtd, int tile) {
    const int kv0 = tile * 64;
#pragma unroll
    for (int i = 0; i < 2; ++i) {
      const int ch = tid + i * 256;  // 0..511 : 64 rows x 8 chunks(16B)
      const int r = ch >> 3, c = ch & 7;
      const int cs = c ^ (r & 7);
      gload16(Kb + (bhN + kv0 + r) * HDc + cs * 8, ksd + ch * 8);
      gload16(Vg + (bhHD + r) * Nc + kv0 + cs * 8, vtd + ch * 8);
    }
  };

  stage(Ks[0], Vt[0], 0);
  int cur = 0;
  for (int t = 0; t < Nc / 64; ++t) {
    __syncthreads();  // drains vmcnt+lgkm: tile visible; prev reads closed
    if (t < Nc / 64 - 1) stage(Ks[cur ^ 1], Vt[cur ^ 1], t + 1);

    const uint16_t* ksp = &Ks[cur][0];
    const uint16_t* vtp = &Vt[cur][0];

    __builtin_amdgcn_s_setprio(1);
    // PV(prev tile): pure-register MFMAs — fill the pipe post-barrier
#pragma unroll
    for (int df = 0; df < 2; ++df)
#pragma unroll
      for (int m = 0; m < 4; ++m)
        O16[df] = MFMA32(vfP[df][m], paP[m], O16[df]);

    // QK^T(t): St[c] reg r = S'[kv = c*32 + (r&3) + 8*(r>>2) + 4*hi][q=l31]
    f32x16 St[2];
#pragma unroll
    for (int c = 0; c < 2; ++c) {
      {
        bf16x8 kf = *(const bf16x8*)(&ksp[(c * 32 + l31) * 64 + ((hi ^ sw) * 8)]);
        St[c] = MFMA32(kf, qf[0], fzv);
      }
#pragma unroll
      for (int ks = 1; ks < 4; ++ks) {
        bf16x8 kf = *(const bf16x8*)(&ksp[(c * 32 + l31) * 64 +
                                          (((ks * 2 + hi) ^ sw) * 8)]);
        St[c] = MFMA32(kf, qf[ks], St[c]);
      }
    }
    __builtin_amdgcn_s_setprio(0);

    // P = exp2(S') directly (no max subtraction — r15 rationale); the QK
    // result latency is hidden under the 8 PV MFMAs above.
#pragma unroll
    for (int r = 0; r < 16; ++r) {
      St[0][r] = fexp2(St[0][r]);
      St[1][r] = fexp2(St[1][r]);
    }

    // denominator on the VALU pipe (partner combine deferred to epilogue)
    {
      f32x16 sv = St[0] + St[1];
      f32x4 s4;
#pragma unroll
      for (int j = 0; j < 4; ++j)
        s4[j] = (sv[j] + sv[j + 4]) + (sv[j + 8] + sv[j + 12]);
      lrow += (s4[0] + s4[1]) + (s4[2] + s4[3]);
    }

    // pack P -> paP (consumed by PV at iter t+1). Window m: kv [16m,16m+16);
    // k-slot hi*8+j maps to kv = 16m + 4hi + (j&3) + 8*(j>>2).
#pragma unroll
    for (int m = 0; m < 4; ++m) {
      const int c = m >> 1, rr = (m & 1) * 2;
#pragma unroll
      for (int j = 0; j < 4; ++j) {
        paP[m][j] = (__bf16)St[c][rr * 4 + j];
        paP[m][j + 4] = (__bf16)St[c][rr * 4 + 4 + j];
      }
    }

    // V fragments for this tile -> vfP (used by PV at iter t+1). These reads
    // complete before the next barrier; Vt[cur] is only overwritten by the
    // stage issued after that barrier.
#pragma unroll
    for (int df = 0; df < 2; ++df) {
      const int drow = df * 32 + l31;
#pragma unroll
      for (int m = 0; m < 4; ++m)
        vfP[df][m] = *(const bf16x8*)(&vtp[drow * 64 + (((2 * m + hi) ^ sw) * 8)]);
    }
    cur ^= 1;
  }

  // final PV (tile 63)
#pragma unroll
  for (int df = 0; df < 2; ++df)
#pragma unroll
    for (int m = 0; m < 4; ++m)
      O16[df] = MFMA32(vfP[df][m], paP[m], O16[df]);

  // epilogue: partner-combine lrow, per-lane normalize (q = l31), 8B stores.
  // O16[df] reg r -> d = df*32 + (r&3) + 8*(r>>2) + 4*hi.
  lrow += __shfl_xor(lrow, 32);
  const int b = bh >> 4, h = bh & 15;
  const float inv = 1.f / lrow;
  const int n = q0 + wave * 32 + l31;
  uint16_t* orow = Ob + ((size_t)b * Nc + n) * Dc + h * HDc;
#pragma unroll
  for (int df = 0; df < 2; ++df)
#pragma unroll
    for (int r2 = 0; r2 < 4; ++r2) {
      uint2 pv;
      pv.x = (uint32_t)f2bf(O16[df][r2 * 4 + 0] * inv) |
             ((uint32_t)f2bf(O16[df][r2 * 4 + 1] * inv) << 16);
      pv.y = (uint32_t)f2bf(O16[df][r2 * 4 + 2] * inv) |
             ((uint32_t)f2bf(O16[df][r2 * 4 + 3] * inv) << 16);
      *(uint2*)(orow + df * 32 + r2 * 8 + hi * 4) = pv;
    }
}

extern "C" void kernel_launch(void* const* d_in, const int* in_sizes, int n_in,
                              void* d_out, int out_size, void* d_ws, size_t ws_size,
                              hipStream_t stream) {
  const float* x = (const float*)d_in[0];      // [B,N,D] f32
  const float* rot = (const float*)d_in[1];    // [B,N,D,2] f32
  const float* Wqkv = (const float*)d_in[2];   // [3D,D] f32
  const float* Wout = (const float*)d_in[3];   // [D,D] f32
  const float* bout = (const float*)d_in[4];   // [D] f32
  float* out = (float*)d_out;                  // [B,N,D] f32

  uint16_t* ws = (uint16_t*)d_ws;
  uint16_t* xb = ws;               // bf16 x; ALIASED with At (safe: xb's last
  uint16_t* At = ws;               // read is gemm1; At first written by attn)
  uint16_t* Qb = ws + XSZ;
  uint16_t* Kb = ws + 2 * XSZ;
  uint16_t* Vg = ws + 3 * XSZ;     // transposed [B,H,HD,N], kv pre-interleaved
  uint16_t* Wqb = ws + 4 * XSZ;
  uint16_t* Wob = ws + 4 * XSZ + W1SZ;
  // total: 4*XSZ + W1SZ + W2SZ = 71,303,168 elems = 142.6 MB

  dim3 blk(256);
  const size_t CVN = XSZ / 8 + W1SZ / 8 + W2SZ / 8;
  cvt_all<<<dim3((unsigned)((CVN + 255) / 256)), blk, 0, stream>>>(
      x, Wqkv, Wout, xb, Wqb, Wob);

  gemm_bt<0><<<dim3((3 * Dc) / 128, (Bc * Nc) / 128), blk, 0, stream>>>(
      xb, Wqb, Dc, rot, Qb, Kb, Vg, nullptr, nullptr);
  attn_fa<<<dim3((Nc / 128) * (Bc * Hc)), blk, 0, stream>>>(Qb, Kb, Vg, At);
  gemm_bt<1><<<dim3(Dc / 128, (Bc * Nc) / 128), blk, 0, stream>>>(
      At, Wob, Dc, nullptr, nullptr, nullptr, nullptr, bout, out);
}

// Round 22
// 540.107 us; speedup vs baseline: 1.0347x; 1.0347x over previous
//
#include <hip/hip_runtime.h>
#include <hip/hip_bf16.h>
#include <stdint.h>
#include <stddef.h>

typedef __attribute__((ext_vector_type(8))) __bf16 bf16x8;
typedef __attribute__((ext_vector_type(4))) float f32x4;
typedef __attribute__((ext_vector_type(16))) float f32x16;

#define MFMA16(a, b, c) __builtin_amdgcn_mfma_f32_16x16x32_bf16((a), (b), (c), 0, 0, 0)
#define MFMA32(a, b, c) __builtin_amdgcn_mfma_f32_32x32x16_bf16((a), (b), (c), 0, 0, 0)

static constexpr int Bc = 4, Nc = 4096, Dc = 1024, Hc = 16, HDc = 64;
static constexpr size_t XSZ = (size_t)Bc * Nc * Dc;   // 16,777,216
static constexpr size_t W1SZ = (size_t)3 * Dc * Dc;   //  3,145,728
static constexpr size_t W2SZ = (size_t)Dc * Dc;       //  1,048,576

__device__ __forceinline__ uint16_t f2bf(float f) {
  __bf16 h = (__bf16)f;
  return __builtin_bit_cast(uint16_t, h);
}

// raw v_exp_f32 (no libm edge-case code; inputs here are finite, bounded)
__device__ __forceinline__ float fexp2(float x) {
#if __has_builtin(__builtin_amdgcn_exp2f)
  return __builtin_amdgcn_exp2f(x);
#else
  return __builtin_exp2f(x);
#endif
}

// async global->LDS, 16B per lane. LDS dest must be wave-uniform base + lane*16.
__device__ __forceinline__ void gload16(const void* g, void* l) {
  __builtin_amdgcn_global_load_lds(
      (__attribute__((address_space(1))) void*)(g),
      (__attribute__((address_space(3))) void*)(l), 16, 0, 0);
}

// ---------------------------------------------------------------------------
// fused f32 -> bf16 convert for x, W_qkv, W_out (one launch, flat-indexed)
// ---------------------------------------------------------------------------
__global__ __launch_bounds__(256) void cvt_all(
    const float* __restrict__ x, const float* __restrict__ w1,
    const float* __restrict__ w2, uint16_t* __restrict__ xb,
    uint16_t* __restrict__ w1b, uint16_t* __restrict__ w2b) {
  const size_t XN = XSZ / 8, W1N = W1SZ / 8, W2N = W2SZ / 8;
  size_t i = (size_t)blockIdx.x * 256 + threadIdx.x;
  const float* src;
  uint16_t* dst;
  if (i < XN) {
    src = x; dst = xb;
  } else if (i < XN + W1N) {
    src = w1; dst = w1b; i -= XN;
  } else if (i < XN + W1N + W2N) {
    src = w2; dst = w2b; i -= XN + W1N;
  } else {
    return;
  }
  const float4 a = *(const float4*)(src + i * 8);
  const float4 b = *(const float4*)(src + i * 8 + 4);
  union { uint16_t u[8]; uint4 v; } o;
  o.u[0] = f2bf(a.x); o.u[1] = f2bf(a.y); o.u[2] = f2bf(a.z); o.u[3] = f2bf(a.w);
  o.u[4] = f2bf(b.x); o.u[5] = f2bf(b.y); o.u[6] = f2bf(b.z); o.u[7] = f2bf(b.w);
  *(uint4*)(dst + i * 8) = o.v;
}

// ---------------------------------------------------------------------------
// BT-GEMM: C[m, e] = sum_k A[m, k] * Bw[e, k].  128x128 tile, BK=64, 4 waves.
// Single-buffer 2-barrier staging (r17-proven; r21's 64KB dbuf halved
// residency, net loss). EPI=0: QKV epilogue -> RoPE (f32 rot) -> Q/K
// [B,H,N,HD] bf16 (Q pre-scaled 0.125*log2e), V [B,H,HD,N] bf16 with
// kv pre-interleaved per 64-tile. EPI=1: bias add -> f32 out.
// ---------------------------------------------------------------------------
template <int EPI>
__global__ __launch_bounds__(256, 2) void gemm_bt(
    const uint16_t* __restrict__ A, const uint16_t* __restrict__ Bw, int K,
    const float* __restrict__ rot, uint16_t* __restrict__ Qb,
    uint16_t* __restrict__ Kb, uint16_t* __restrict__ Vg,
    const float* __restrict__ bias, float* __restrict__ Out) {
  __shared__ __align__(16) uint16_t As[128 * 64];
  __shared__ __align__(16) uint16_t Bs[128 * 64];
  const int tid = threadIdx.x;
  const int lane = tid & 63, wave = tid >> 6;
  const int l15 = lane & 15, g = lane >> 4;
  const int wr = wave >> 1, wc = wave & 1;
  const int m0 = blockIdx.y * 128;
  const int n0 = blockIdx.x * 128;

  f32x4 acc[4][4];
  const f32x4 fz = {0.f, 0.f, 0.f, 0.f};
#pragma unroll
  for (int i = 0; i < 4; ++i)
#pragma unroll
    for (int j = 0; j < 4; ++j) acc[i][j] = fz;

  for (int kt = 0; kt < K; kt += 64) {
    __syncthreads();  // previous iter's LDS reads done before overwrite
#pragma unroll
    for (int i = 0; i < 4; ++i) {
      const int chunk = tid + i * 256;  // 0..1023 : 128 rows x 8 chunks(16B)
      const int r = chunk >> 3, c = chunk & 7;
      const int cs = c ^ (r & 7);  // pre-swizzled source (linear LDS dest)
      gload16(A + (size_t)(m0 + r) * K + kt + cs * 8, &As[chunk * 8]);
      gload16(Bw + (size_t)(n0 + r) * K + kt + cs * 8, &Bs[chunk * 8]);
    }
    __syncthreads();  // implies vmcnt(0): staged data visible

    bf16x8 af[4][2], bfr[4][2];
#pragma unroll
    for (int mi = 0; mi < 4; ++mi)
#pragma unroll
      for (int kk = 0; kk < 2; ++kk) {
        const int r = wr * 64 + mi * 16 + l15;
        const int ca = (kk * 4 + g) ^ (r & 7);
        af[mi][kk] = *(const bf16x8*)((const char*)As + r * 128 + ca * 16);
        const int r2 = wc * 64 + mi * 16 + l15;
        const int cb = (kk * 4 + g) ^ (r2 & 7);
        bfr[mi][kk] = *(const bf16x8*)((const char*)Bs + r2 * 128 + cb * 16);
      }
#pragma unroll
    for (int mi = 0; mi < 4; ++mi)
#pragma unroll
      for (int nj = 0; nj < 4; ++nj)
#pragma unroll
        for (int kk = 0; kk < 2; ++kk)
          acc[mi][nj] = MFMA16(af[mi][kk], bfr[nj][kk], acc[mi][nj]);
  }

  if (EPI == 0) {
    // C rows m -> (b, n); cols e -> (part, h, hd). RoPE pair is lane^1.
    const int b = m0 >> 12;  // 4096 rows per batch, 128 | 4096 -> uniform
#pragma unroll
    for (int nj = 0; nj < 4; ++nj) {
      const int e = n0 + wc * 64 + nj * 16 + l15;
      const int part = e >> 10;           // wave-uniform (16-col tile)
      const int d = e & 1023;
      const int h = d >> 6, hd = d & 63;
      // exp2-domain: fold 0.125*log2(e) into Q
      const float sc = (part == 0) ? 0.18033688011112042f : 1.0f;
#pragma unroll
      for (int mi = 0; mi < 4; ++mi) {
        if (part == 2) {
          // V transposed [B,H,HD,N], kv pre-interleaved per 64-tile:
          // pack of 4 consecutive n at 4-aligned nb lands contiguously at pos.
          const int nb = (m0 & 4095) + wr * 64 + mi * 16 + g * 4;
          const int vv = nb & 63;
          const int pos = (nb & ~63) + (2 * (vv >> 4) + ((vv >> 2) & 1)) * 8 +
                          ((vv >> 3) & 1) * 4;
          uint2 pv;
          pv.x = (uint32_t)f2bf(acc[mi][nj][0]) |
                 ((uint32_t)f2bf(acc[mi][nj][1]) << 16);
          pv.y = (uint32_t)f2bf(acc[mi][nj][2]) |
                 ((uint32_t)f2bf(acc[mi][nj][3]) << 16);
          *(uint2*)(Vg + ((size_t)(b * Hc + h) * HDc + hd) * Nc + pos) = pv;
        } else {
          uint16_t* dst = (part == 0) ? Qb : Kb;
          const size_t base = ((size_t)(b * Hc + h) * Nc) * HDc + hd;
#pragma unroll
          for (int rg = 0; rg < 4; ++rg) {
            const int m = m0 + wr * 64 + mi * 16 + g * 4 + rg;
            const int n = m & (Nc - 1);
            const float val = acc[mi][nj][rg];
            const float partner = __shfl_xor(val, 1);
            const float x2 = (e & 1) ? partner : -partner;
            const float2 cs =
                *(const float2*)(rot + ((size_t)(b * Nc + n) * Dc + d) * 2);
            dst[base + (size_t)n * HDc] = f2bf((val * cs.x + x2 * cs.y) * sc);
          }
        }
      }
    }
  } else {
#pragma unroll
    for (int nj = 0; nj < 4; ++nj) {
      const int e = n0 + wc * 64 + nj * 16 + l15;
      const float bia = bias[e];
#pragma unroll
      for (int mi = 0; mi < 4; ++mi)
#pragma unroll
        for (int rg = 0; rg < 4; ++rg) {
          const int m = m0 + wr * 64 + mi * 16 + g * 4 + rg;
          Out[(size_t)m * Dc + e] = acc[mi][nj][rg] + bia;
        }
    }
  }
}

// ---------------------------------------------------------------------------
// Flash attention — best-known config (r21 attn, measured 305us):
// 32x32x16 MFMA, in-register P, no-max exp2 softmax, VALU denominator with
// epilogue partner-combine, T15 PV-deferral, runtime-cur dbuf,
// launch_bounds(256,3), XCD-clustered grid, pre-interleaved V via
// global_load_lds.
// ---------------------------------------------------------------------------
__global__ __launch_bounds__(256, 3) void attn_fa(
    const uint16_t* __restrict__ Qb, const uint16_t* __restrict__ Kb,
    const uint16_t* __restrict__ Vg, uint16_t* __restrict__ Ob) {
  __shared__ __align__(16) uint16_t Ks[2][64 * 64];  // [kv][d], chunk-swizzled
  __shared__ __align__(16) uint16_t Vt[2][64 * 64];  // [d][kv-interleaved]
  const int tid = threadIdx.x;
  const int lane = tid & 63, wave = tid >> 6;
  const int l31 = lane & 31, hi = lane >> 5;
  const int sw = l31 & 7;  // swizzle index (row&7 for all row sets used)
  // XCD-clustered bijective remap: id%8 = XCD slot; all 32 q-blocks of a bh
  // land on one XCD -> that L2 only holds its own 8 bh's K/V (~6MB).
  const int id = blockIdx.x;
  const int kk2 = id >> 3;
  const int bh = (id & 7) + 8 * (kk2 >> 5);
  const int q0 = (kk2 & 31) * 128;
  const size_t bhN = (size_t)bh * Nc;
  const size_t bhHD = (size_t)bh * HDc;

  // Q B-fragments (col = q = l31, k(d) = ks*16 + hi*8 + j), register-resident
  bf16x8 qf[4];
#pragma unroll
  for (int ks = 0; ks < 4; ++ks)
    qf[ks] = *(const bf16x8*)(Qb + (bhN + q0 + wave * 32 + l31) * HDc +
                              ks * 16 + hi * 8);

  // persistent zero C-operand for the QK^T MFMA chain
  const f32x16 fzv = {};

  f32x16 O16[2] = {{}, {}};
  float lrow = 0.f;  // per-lane partial; partner (^32) combined in epilogue

  // deferred-PV state: previous tile's P fragments and V fragments.
  // Zero-init so the first iteration's PV(-1) contributes exactly 0.
  bf16x8 paP[4], vfP[2][4];
  {
    const bf16x8 bz = {};
#pragma unroll
    for (int m = 0; m < 4; ++m) { paP[m] = bz; vfP[0][m] = bz; vfP[1][m] = bz; }
  }

  // stage K and V (both gload_lds: linear dest, pre-swizzled source; V's
  // interleave was already applied by the gemm epilogue).
  auto stage = [&](uint16_t* ksd, uint16_t* vtd, int tile) {
    const int kv0 = tile * 64;
#pragma unroll
    for (int i = 0; i < 2; ++i) {
      const int ch = tid + i * 256;  // 0..511 : 64 rows x 8 chunks(16B)
      const int r = ch >> 3, c = ch & 7;
      const int cs = c ^ (r & 7);
      gload16(Kb + (bhN + kv0 + r) * HDc + cs * 8, ksd + ch * 8);
      gload16(Vg + (bhHD + r) * Nc + kv0 + cs * 8, vtd + ch * 8);
    }
  };

  stage(Ks[0], Vt[0], 0);
  int cur = 0;
  for (int t = 0; t < Nc / 64; ++t) {
    __syncthreads();  // drains vmcnt+lgkm: tile visible; prev reads closed
    if (t < Nc / 64 - 1) stage(Ks[cur ^ 1], Vt[cur ^ 1], t + 1);

    const uint16_t* ksp = &Ks[cur][0];
    const uint16_t* vtp = &Vt[cur][0];

    __builtin_amdgcn_s_setprio(1);
    // PV(prev tile): pure-register MFMAs — fill the pipe post-barrier
#pragma unroll
    for (int df = 0; df < 2; ++df)
#pragma unroll
      for (int m = 0; m < 4; ++m)
        O16[df] = MFMA32(vfP[df][m], paP[m], O16[df]);

    // QK^T(t): St[c] reg r = S'[kv = c*32 + (r&3) + 8*(r>>2) + 4*hi][q=l31]
    f32x16 St[2];
#pragma unroll
    for (int c = 0; c < 2; ++c) {
      {
        bf16x8 kf = *(const bf16x8*)(&ksp[(c * 32 + l31) * 64 + ((hi ^ sw) * 8)]);
        St[c] = MFMA32(kf, qf[0], fzv);
      }
#pragma unroll
      for (int ks = 1; ks < 4; ++ks) {
        bf16x8 kf = *(const bf16x8*)(&ksp[(c * 32 + l31) * 64 +
                                          (((ks * 2 + hi) ^ sw) * 8)]);
        St[c] = MFMA32(kf, qf[ks], St[c]);
      }
    }
    __builtin_amdgcn_s_setprio(0);

    // P = exp2(S') directly (no max subtraction — r15 rationale); the QK
    // result latency is hidden under the 8 PV MFMAs above.
#pragma unroll
    for (int r = 0; r < 16; ++r) {
      St[0][r] = fexp2(St[0][r]);
      St[1][r] = fexp2(St[1][r]);
    }

    // denominator on the VALU pipe (partner combine deferred to epilogue)
    {
      f32x16 sv = St[0] + St[1];
      f32x4 s4;
#pragma unroll
      for (int j = 0; j < 4; ++j)
        s4[j] = (sv[j] + sv[j + 4]) + (sv[j + 8] + sv[j + 12]);
      lrow += (s4[0] + s4[1]) + (s4[2] + s4[3]);
    }

    // pack P -> paP (consumed by PV at iter t+1). Window m: kv [16m,16m+16);
    // k-slot hi*8+j maps to kv = 16m + 4hi + (j&3) + 8*(j>>2).
#pragma unroll
    for (int m = 0; m < 4; ++m) {
      const int c = m >> 1, rr = (m & 1) * 2;
#pragma unroll
      for (int j = 0; j < 4; ++j) {
        paP[m][j] = (__bf16)St[c][rr * 4 + j];
        paP[m][j + 4] = (__bf16)St[c][rr * 4 + 4 + j];
      }
    }

    // V fragments for this tile -> vfP (used by PV at iter t+1). These reads
    // complete before the next barrier; Vt[cur] is only overwritten by the
    // stage issued after that barrier.
#pragma unroll
    for (int df = 0; df < 2; ++df) {
      const int drow = df * 32 + l31;
#pragma unroll
      for (int m = 0; m < 4; ++m)
        vfP[df][m] = *(const bf16x8*)(&vtp[drow * 64 + (((2 * m + hi) ^ sw) * 8)]);
    }
    cur ^= 1;
  }

  // final PV (tile 63)
#pragma unroll
  for (int df = 0; df < 2; ++df)
#pragma unroll
    for (int m = 0; m < 4; ++m)
      O16[df] = MFMA32(vfP[df][m], paP[m], O16[df]);

  // epilogue: partner-combine lrow, per-lane normalize (q = l31), 8B stores.
  // O16[df] reg r -> d = df*32 + (r&3) + 8*(r>>2) + 4*hi.
  lrow += __shfl_xor(lrow, 32);
  const int b = bh >> 4, h = bh & 15;
  const float inv = 1.f / lrow;
  const int n = q0 + wave * 32 + l31;
  uint16_t* orow = Ob + ((size_t)b * Nc + n) * Dc + h * HDc;
#pragma unroll
  for (int df = 0; df < 2; ++df)
#pragma unroll
    for (int r2 = 0; r2 < 4; ++r2) {
      uint2 pv;
      pv.x = (uint32_t)f2bf(O16[df][r2 * 4 + 0] * inv) |
             ((uint32_t)f2bf(O16[df][r2 * 4 + 1] * inv) << 16);
      pv.y = (uint32_t)f2bf(O16[df][r2 * 4 + 2] * inv) |
             ((uint32_t)f2bf(O16[df][r2 * 4 + 3] * inv) << 16);
      *(uint2*)(orow + df * 32 + r2 * 8 + hi * 4) = pv;
    }
}

extern "C" void kernel_launch(void* const* d_in, const int* in_sizes, int n_in,
                              void* d_out, int out_size, void* d_ws, size_t ws_size,
                              hipStream_t stream) {
  const float* x = (const float*)d_in[0];      // [B,N,D] f32
  const float* rot = (const float*)d_in[1];    // [B,N,D,2] f32
  const float* Wqkv = (const float*)d_in[2];   // [3D,D] f32
  const float* Wout = (const float*)d_in[3];   // [D,D] f32
  const float* bout = (const float*)d_in[4];   // [D] f32
  float* out = (float*)d_out;                  // [B,N,D] f32

  uint16_t* ws = (uint16_t*)d_ws;
  uint16_t* xb = ws;               // bf16 x; ALIASED with At (safe: xb's last
  uint16_t* At = ws;               // read is gemm1; At first written by attn)
  uint16_t* Qb = ws + XSZ;
  uint16_t* Kb = ws + 2 * XSZ;
  uint16_t* Vg = ws + 3 * XSZ;     // transposed [B,H,HD,N], kv pre-interleaved
  uint16_t* Wqb = ws + 4 * XSZ;
  uint16_t* Wob = ws + 4 * XSZ + W1SZ;
  // total: 4*XSZ + W1SZ + W2SZ = 71,303,168 elems = 142.6 MB

  dim3 blk(256);
  const size_t CVN = XSZ / 8 + W1SZ / 8 + W2SZ / 8;
  cvt_all<<<dim3((unsigned)((CVN + 255) / 256)), blk, 0, stream>>>(
      x, Wqkv, Wout, xb, Wqb, Wob);

  gemm_bt<0><<<dim3((3 * Dc) / 128, (Bc * Nc) / 128), blk, 0, stream>>>(
      xb, Wqb, Dc, rot, Qb, Kb, Vg, nullptr, nullptr);
  attn_fa<<<dim3((Nc / 128) * (Bc * Hc)), blk, 0, stream>>>(Qb, Kb, Vg, At);
  gemm_bt<1><<<dim3(Dc / 128, (Bc * Nc) / 128), blk, 0, stream>>>(
      At, Wob, Dc, nullptr, nullptr, nullptr, nullptr, bout, out);
}